// Round 1
// baseline (322.386 us; speedup 1.0000x reference)
//
#include <hip/hip_runtime.h>
#include <stdint.h>

typedef short bf16x8 __attribute__((ext_vector_type(8)));
typedef float f32x4 __attribute__((ext_vector_type(4)));

__device__ __forceinline__ uint32_t asu(float f) { union { float f; uint32_t u; } c; c.f = f; return c.u; }

__device__ __forceinline__ unsigned short f32_to_bf16(float f) {
  uint32_t u = asu(f);
  uint32_t r = u + 0x7FFFu + ((u >> 16) & 1u);
  return (unsigned short)(r >> 16);
}

__device__ __forceinline__ float fast_tanh(float x) {
  // tanh(x) = 1 - 2/(e^{2x}+1); e^{2x} = 2^(x*2*log2(e))
  float e = __builtin_amdgcn_exp2f(x * 2.8853900817779268f);
  return 1.0f - 2.0f * __builtin_amdgcn_rcpf(e + 1.0f);
}

#define GLD16(g, l)                                                                   \
  __builtin_amdgcn_global_load_lds((const __attribute__((address_space(1))) void*)(g), \
                                   (__attribute__((address_space(3))) void*)(l), 16, 0, 0)

// ---------------- zero scratch ----------------
__global__ void zero_f32(float* __restrict__ p, int n) {
  int i = blockIdx.x * 256 + threadIdx.x;
  if (i < n) p[i] = 0.f;
}

// ---------------- W1k transpose + bf16 convert: W1kt[j][k] = bf16(W1[1024+k][j]) ----------------
__global__ void transpose_w1k(const float* __restrict__ W1, unsigned short* __restrict__ W1kt) {
  __shared__ float t[64][65];
  const int kb = blockIdx.x * 64;
  const int jb = blockIdx.y * 64;
  const int c = threadIdx.x & 63;
  const int r = threadIdx.x >> 6;  // 0..3
#pragma unroll
  for (int i = 0; i < 16; ++i) {
    const int k = i * 4 + r;
    t[k][c] = W1[(size_t)(1024 + kb + k) * 1024 + (jb + c)];
  }
  __syncthreads();
#pragma unroll
  for (int i = 0; i < 16; ++i) {
    const int j = i * 4 + r;
    W1kt[(size_t)(jb + j) * 1024 + (kb + c)] = f32_to_bf16(t[c][j]);
  }
}

// ---------------- qterm[b][j] = b1[j] + sum_k query[b][k]*W1[k][j] ----------------
__global__ void qterm_kernel(const float* __restrict__ query, const float* __restrict__ W1,
                             const float* __restrict__ b1, float* __restrict__ qterm) {
  const int b = blockIdx.y;
  const int j = blockIdx.x * 256 + threadIdx.x;
  const float* q = query + b * 1024;
  float acc = b1[j];
#pragma unroll 8
  for (int k = 0; k < 1024; ++k) acc += q[k] * W1[(size_t)k * 1024 + j];
  qterm[b * 1024 + j] = acc;
}

// ---------------- fused GEMM: scores[m] = sum_j tanh(keys@W1k + qterm + cov*W1c)[m][j] * W2[j] ----------------
__global__ __launch_bounds__(256) void gemm_score_kernel(
    const float* __restrict__ keys, const unsigned short* __restrict__ W1kt,
    const float* __restrict__ qterm, const float* __restrict__ coverage,
    const float* __restrict__ W1, const float* __restrict__ W2, float* __restrict__ scores) {
  __shared__ float Alds[128 * 64];           // fp32 A tile (rows x k), 32KB
  __shared__ unsigned short Blds[128 * 64];  // bf16 B^T tile (cols x k), 16KB
  const int tid = threadIdx.x;
  const int bn = blockIdx.x;  // 0..7
  const int bm = blockIdx.y;  // 0..255
  const int row0 = bm * 128;
  const int col0 = bn * 128;
  const int lane = tid & 63;
  const int w = tid >> 6;
  const int wm = w >> 1, wn = w & 1;
  const int q4 = lane >> 4;
  const int c16 = lane & 15;

  const int arow = tid >> 4;        // 0..15
  const int acol = (tid & 15) * 4;  // fp32 elems
  const int brow = tid >> 3;        // 0..31
  const int bcol = (tid & 7) * 8;   // bf16 elems

  f32x4 acc[4][4];
  const f32x4 zz = {0.f, 0.f, 0.f, 0.f};
#pragma unroll
  for (int i = 0; i < 4; ++i)
#pragma unroll
    for (int j = 0; j < 4; ++j) acc[i][j] = zz;

  const float* gA0 = keys + (size_t)(row0 + arow) * 1024 + acol;
  const unsigned short* gB0 = W1kt + (size_t)(col0 + brow) * 1024 + bcol;
  float* lA0 = Alds + arow * 64 + acol;
  unsigned short* lB0 = Blds + brow * 64 + bcol;

  for (int kt = 0; kt < 16; ++kt) {
    const int k0 = kt * 64;
#pragma unroll
    for (int c = 0; c < 8; ++c) GLD16(gA0 + (size_t)c * 16 * 1024 + k0, lA0 + c * 16 * 64);
#pragma unroll
    for (int c = 0; c < 4; ++c) GLD16(gB0 + (size_t)c * 32 * 1024 + k0, lB0 + c * 32 * 64);
    __syncthreads();
#pragma unroll
    for (int kk = 0; kk < 2; ++kk) {
      bf16x8 af[4];
#pragma unroll
      for (int mi = 0; mi < 4; ++mi) {
        const float* ap = Alds + (wm * 64 + mi * 16 + c16) * 64 + kk * 32 + q4 * 8;
        f32x4 f0 = *(const f32x4*)ap;
        f32x4 f1 = *(const f32x4*)(ap + 4);
        union { bf16x8 v; uint32_t u[4]; } pk;
        pk.u[0] = __builtin_amdgcn_perm(asu(f0.y), asu(f0.x), 0x07060302u);
        pk.u[1] = __builtin_amdgcn_perm(asu(f0.w), asu(f0.z), 0x07060302u);
        pk.u[2] = __builtin_amdgcn_perm(asu(f1.y), asu(f1.x), 0x07060302u);
        pk.u[3] = __builtin_amdgcn_perm(asu(f1.w), asu(f1.z), 0x07060302u);
        af[mi] = pk.v;
      }
      bf16x8 bfr[4];
#pragma unroll
      for (int ni = 0; ni < 4; ++ni)
        bfr[ni] = *(const bf16x8*)(Blds + (wn * 64 + ni * 16 + c16) * 64 + kk * 32 + q4 * 8);
#pragma unroll
      for (int mi = 0; mi < 4; ++mi)
#pragma unroll
        for (int ni = 0; ni < 4; ++ni)
          acc[mi][ni] = __builtin_amdgcn_mfma_f32_16x16x32_bf16(af[mi], bfr[ni], acc[mi][ni], 0, 0, 0);
    }
    __syncthreads();
  }

  // epilogue: v = acc + qterm[b][j] + cov[m]*W1c[j]; score_partial[m] += tanh(v)*W2[j]
  const int b = row0 >> 11;  // 2048 rows per batch; 128 | 2048 so block is batch-uniform
  float qtv[4], w1cv[4], w2v[4];
#pragma unroll
  for (int ni = 0; ni < 4; ++ni) {
    const int j = col0 + wn * 64 + ni * 16 + c16;
    qtv[ni] = qterm[b * 1024 + j];
    w1cv[ni] = W1[(size_t)2048 * 1024 + j];
    w2v[ni] = W2[j];
  }
  float covv[4][4];
#pragma unroll
  for (int mi = 0; mi < 4; ++mi)
#pragma unroll
    for (int r = 0; r < 4; ++r)
      covv[mi][r] = coverage[row0 + wm * 64 + mi * 16 + q4 * 4 + r];

#pragma unroll
  for (int mi = 0; mi < 4; ++mi) {
#pragma unroll
    for (int r = 0; r < 4; ++r) {
      float p = 0.f;
#pragma unroll
      for (int ni = 0; ni < 4; ++ni) {
        float v = acc[mi][ni][r] + qtv[ni] + covv[mi][r] * w1cv[ni];
        p += fast_tanh(v) * w2v[ni];
      }
      p += __shfl_xor(p, 1);
      p += __shfl_xor(p, 2);
      p += __shfl_xor(p, 4);
      p += __shfl_xor(p, 8);
      if (c16 == 0) atomicAdd(&scores[row0 + wm * 64 + mi * 16 + q4 * 4 + r], p);
    }
  }
}

// ---------------- softmax over L per batch; writes attention to d_out ----------------
__global__ void softmax_kernel(const float* __restrict__ scores, float* __restrict__ att) {
  const int b = blockIdx.x;
  const int tid = threadIdx.x;
  const float* s = scores + b * 2048;
  float* a = att + b * 2048;
  __shared__ float red[4];
  float mx = -1e30f;
  for (int l = tid; l < 2048; l += 256) mx = fmaxf(mx, s[l]);
#pragma unroll
  for (int o = 1; o < 64; o <<= 1) mx = fmaxf(mx, __shfl_xor(mx, o));
  if ((tid & 63) == 0) red[tid >> 6] = mx;
  __syncthreads();
  mx = fmaxf(fmaxf(red[0], red[1]), fmaxf(red[2], red[3]));
  __syncthreads();
  float sum = 0.f;
  for (int l = tid; l < 2048; l += 256) {
    float e = __expf(s[l] - mx);
    a[l] = e;
    sum += e;
  }
#pragma unroll
  for (int o = 1; o < 64; o <<= 1) sum += __shfl_xor(sum, o);
  if ((tid & 63) == 0) red[tid >> 6] = sum;
  __syncthreads();
  sum = red[0] + red[1] + red[2] + red[3];
  const float inv = 1.0f / sum;
  for (int l = tid; l < 2048; l += 256) a[l] *= inv;
}

// ---------------- ctx_pre[b][j] = sum_l att[b][l] * keys[b][l][j] ----------------
__global__ void ctxpre_kernel(const float* __restrict__ keys, const float* __restrict__ att,
                              float* __restrict__ ctx_pre) {
  const int b = blockIdx.x;   // 16
  const int sl = blockIdx.y;  // 32 slices of 64 rows
  const int tid = threadIdx.x;
  const float* ab = att + b * 2048 + sl * 64;
  const f32x4* kb = (const f32x4*)(keys + ((size_t)b * 2048 + sl * 64) * 1024) + tid;
  f32x4 acc = {0.f, 0.f, 0.f, 0.f};
#pragma unroll 4
  for (int l = 0; l < 64; ++l) acc += kb[(size_t)l * 256] * ab[l];
  float* cp = ctx_pre + b * 1024 + tid * 4;
  atomicAdd(cp + 0, acc.x);
  atomicAdd(cp + 1, acc.y);
  atomicAdd(cp + 2, acc.z);
  atomicAdd(cp + 3, acc.w);
}

// ---------------- context[b][h] = sum_j ctx_pre[b][j] * Wr[j][h] ----------------
__global__ void context_kernel(const float* __restrict__ ctx_pre, const float* __restrict__ Wr,
                               float* __restrict__ out) {
  const int b = blockIdx.y;
  const int h = blockIdx.x * 256 + threadIdx.x;
  const float* cp = ctx_pre + b * 1024;
  float acc = 0.f;
#pragma unroll 8
  for (int j = 0; j < 1024; ++j) acc += cp[j] * Wr[(size_t)j * 512 + h];
  out[b * 512 + h] = acc;
}

extern "C" void kernel_launch(void* const* d_in, const int* in_sizes, int n_in, void* d_out,
                              int out_size, void* d_ws, size_t ws_size, hipStream_t stream) {
  const float* query = (const float*)d_in[0];     // (16,1,1024)
  const float* keys = (const float*)d_in[1];      // (16,2048,1024)
  const float* coverage = (const float*)d_in[2];  // (16,2048,1)
  const float* W1 = (const float*)d_in[3];        // (2049,1024)
  const float* b1 = (const float*)d_in[4];        // (1024,)
  const float* W2 = (const float*)d_in[5];        // (1024,1)
  const float* Wr = (const float*)d_in[6];        // (1024,512)
  float* out = (float*)d_out;
  char* ws = (char*)d_ws;

  float* scores = (float*)ws;                              // 32768 f32 @ 0
  float* ctx_pre = (float*)(ws + 131072);                  // 16384 f32
  float* qterm = (float*)(ws + 196608);                    // 16384 f32
  unsigned short* W1kt = (unsigned short*)(ws + 262144);   // 1M bf16 (2MB)

  float* context_out = out;        // 16*512
  float* att_out = out + 8192;     // 16*2048

  zero_f32<<<dim3(192), dim3(256), 0, stream>>>(scores, 49152);  // scores + ctx_pre (contiguous)
  transpose_w1k<<<dim3(16, 16), dim3(256), 0, stream>>>(W1, W1kt);
  qterm_kernel<<<dim3(4, 16), dim3(256), 0, stream>>>(query, W1, b1, qterm);
  gemm_score_kernel<<<dim3(8, 256), dim3(256), 0, stream>>>(keys, W1kt, qterm, coverage, W1, W2,
                                                            scores);
  softmax_kernel<<<dim3(16), dim3(256), 0, stream>>>(scores, att_out);
  ctxpre_kernel<<<dim3(16, 32), dim3(256), 0, stream>>>(keys, att_out, ctx_pre);
  context_kernel<<<dim3(2, 16), dim3(256), 0, stream>>>(ctx_pre, Wr, context_out);
}

// Round 3
// 319.436 us; speedup vs baseline: 1.0092x; 1.0092x over previous
//
#include <hip/hip_runtime.h>
#include <stdint.h>

typedef short bf16x8 __attribute__((ext_vector_type(8)));
typedef float f32x4 __attribute__((ext_vector_type(4)));
typedef unsigned int u32x4 __attribute__((ext_vector_type(4)));

__device__ __forceinline__ uint32_t asu(float f) { union { float f; uint32_t u; } c; c.f = f; return c.u; }

__device__ __forceinline__ uint32_t bf16rne(float f) {
  uint32_t u = asu(f);
  return (u + 0x7FFFu + ((u >> 16) & 1u)) >> 16;
}
__device__ __forceinline__ uint32_t pack2(float lo, float hi) { return bf16rne(lo) | (bf16rne(hi) << 16); }

__device__ __forceinline__ unsigned short f32_to_bf16(float f) { return (unsigned short)bf16rne(f); }

__device__ __forceinline__ float fast_tanh(float x) {
  float e = __builtin_amdgcn_exp2f(x * 2.8853900817779268f);
  return 1.0f - 2.0f * __builtin_amdgcn_rcpf(e + 1.0f);
}

// ---------------- zero scratch (ctx_pre only) ----------------
__global__ void zero_f32(float* __restrict__ p, int n) {
  int i = blockIdx.x * 256 + threadIdx.x;
  if (i < n) p[i] = 0.f;
}

// ---------------- W1k transpose + bf16 convert: W1kt[j][k] = bf16(W1[1024+k][j]) ----------------
__global__ void transpose_w1k(const float* __restrict__ W1, unsigned short* __restrict__ W1kt) {
  __shared__ float t[64][65];
  const int kb = blockIdx.x * 64;
  const int jb = blockIdx.y * 64;
  const int c = threadIdx.x & 63;
  const int r = threadIdx.x >> 6;  // 0..3
#pragma unroll
  for (int i = 0; i < 16; ++i) {
    const int k = i * 4 + r;
    t[k][c] = W1[(size_t)(1024 + kb + k) * 1024 + (jb + c)];
  }
  __syncthreads();
#pragma unroll
  for (int i = 0; i < 16; ++i) {
    const int j = i * 4 + r;
    W1kt[(size_t)(jb + j) * 1024 + (kb + c)] = f32_to_bf16(t[c][j]);
  }
}

// ---------------- qterm[b][j] = b1[j] + sum_k query[b][k]*W1[k][j] ----------------
__global__ void qterm_kernel(const float* __restrict__ query, const float* __restrict__ W1,
                             const float* __restrict__ b1, float* __restrict__ qterm) {
  const int b = blockIdx.y;
  const int j = blockIdx.x * 256 + threadIdx.x;
  const float* q = query + b * 1024;
  float acc = b1[j];
#pragma unroll 8
  for (int k = 0; k < 1024; ++k) acc += q[k] * W1[(size_t)k * 1024 + j];
  qterm[b * 1024 + j] = acc;
}

// ---------------- fused GEMM + tanh + W2-reduce ----------------
// Block: 512 threads (8 waves), BM=64 rows, full N=1024, full K=1024.
// A (keys rows) resident in LDS as bf16. Swizzle: element (row, byte bo) at
// row*2048 + (bo ^ ((row&7)<<4)) — XOR applied to the FULL offset (no add-carry).
#define MFMA16(a, b, c) __builtin_amdgcn_mfma_f32_16x16x32_bf16(a, b, c, 0, 0, 0)

__global__ __launch_bounds__(512, 2) void gemm_score_kernel(
    const float* __restrict__ keys, const unsigned short* __restrict__ W1kt,
    const float* __restrict__ qterm, const float* __restrict__ coverage,
    const float* __restrict__ W1, const float* __restrict__ W2, float* __restrict__ scores) {
  __shared__ __align__(16) unsigned char Ab[131072];  // 64 rows x 1024 k x bf16, swizzled
  const int tid = threadIdx.x;
  const int row0 = blockIdx.x * 64;
  const int b = row0 >> 11;  // 2048 rows per batch
  const int w = tid >> 6;
  const int lane = tid & 63;
  const int c16 = lane & 15;
  const int q4 = lane >> 4;

  // ---- staging: thread t covers row=t>>3, k-offsets (t&7)*8 + i*64 ----
  const int srow = tid >> 3;
  const int skoff = (tid & 7) * 8;
  const float* gA = keys + (size_t)(row0 + srow) * 1024;
  const int swzw = (srow & 7) << 4;

  // chunk0: k in [0,512)
  f32x4 c0a[8], c0b[8];
#pragma unroll
  for (int i = 0; i < 8; ++i) {
    const int k = i * 64 + skoff;
    c0a[i] = *(const f32x4*)(gA + k);
    c0b[i] = *(const f32x4*)(gA + k + 4);
  }
#pragma unroll
  for (int i = 0; i < 8; ++i) {
    const int k = i * 64 + skoff;
    u32x4 p;
    p.x = pack2(c0a[i].x, c0a[i].y);
    p.y = pack2(c0a[i].z, c0a[i].w);
    p.z = pack2(c0b[i].x, c0b[i].y);
    p.w = pack2(c0b[i].z, c0b[i].w);
    *(u32x4*)(Ab + srow * 2048 + ((k * 2) ^ swzw)) = p;
  }
  // chunk1 loads issued now (k in [512,1024)); consumed after phase 1
  f32x4 c1a[8], c1b[8];
#pragma unroll
  for (int i = 0; i < 8; ++i) {
    const int k = 512 + i * 64 + skoff;
    c1a[i] = *(const f32x4*)(gA + k);
    c1b[i] = *(const f32x4*)(gA + k + 4);
  }
  __syncthreads();

  // fragment addressing
  const int swzr = (c16 & 7) << 4;
  const unsigned short* gB = W1kt + (size_t)(w * 128 + c16) * 1024 + q4 * 8;

  f32x4 acc[4][4];  // [c][mf]
  const f32x4 zz = {0.f, 0.f, 0.f, 0.f};
#pragma unroll
  for (int c = 0; c < 4; ++c)
#pragma unroll
    for (int mf = 0; mf < 4; ++mf) acc[c][mf] = zz;

  // ---- phase 1: ncols 0..3, ks 0..15 (k < 512) ----
#pragma unroll
  for (int ks = 0; ks < 16; ++ks) {
    bf16x8 af[4];
#pragma unroll
    for (int mf = 0; mf < 4; ++mf)
      af[mf] = *(const bf16x8*)(Ab + (mf * 16 + c16) * 2048 + ((ks * 64 + q4 * 16) ^ swzr));
#pragma unroll
    for (int c = 0; c < 4; ++c) {
      bf16x8 bv = *(const bf16x8*)(gB + (size_t)c * 16384 + ks * 32);
#pragma unroll
      for (int mf = 0; mf < 4; ++mf) acc[c][mf] = MFMA16(af[mf], bv, acc[c][mf]);
    }
  }

  // ---- write chunk1 into LDS (disjoint from phase-1 read range; barrier after) ----
#pragma unroll
  for (int i = 0; i < 8; ++i) {
    const int k = 512 + i * 64 + skoff;
    u32x4 p;
    p.x = pack2(c1a[i].x, c1a[i].y);
    p.y = pack2(c1a[i].z, c1a[i].w);
    p.z = pack2(c1b[i].x, c1b[i].y);
    p.w = pack2(c1b[i].z, c1b[i].w);
    *(u32x4*)(Ab + srow * 2048 + ((k * 2) ^ swzw)) = p;
  }
  __syncthreads();

  // epilogue constants
  float covv[4][4];
#pragma unroll
  for (int mf = 0; mf < 4; ++mf)
#pragma unroll
    for (int r = 0; r < 4; ++r) covv[mf][r] = coverage[row0 + mf * 16 + q4 * 4 + r];

  float p_part[4][4];
#pragma unroll
  for (int mf = 0; mf < 4; ++mf)
#pragma unroll
    for (int r = 0; r < 4; ++r) p_part[mf][r] = 0.f;

  // ---- phase 2a: ncols 0..3, ks 16..31 ----
#pragma unroll
  for (int ks = 16; ks < 32; ++ks) {
    bf16x8 af[4];
#pragma unroll
    for (int mf = 0; mf < 4; ++mf)
      af[mf] = *(const bf16x8*)(Ab + (mf * 16 + c16) * 2048 + ((ks * 64 + q4 * 16) ^ swzr));
#pragma unroll
    for (int c = 0; c < 4; ++c) {
      bf16x8 bv = *(const bf16x8*)(gB + (size_t)c * 16384 + ks * 32);
#pragma unroll
      for (int mf = 0; mf < 4; ++mf) acc[c][mf] = MFMA16(af[mf], bv, acc[c][mf]);
    }
  }
  // epilogue for ncols 0..3
#pragma unroll
  for (int c = 0; c < 4; ++c) {
    const int col = w * 128 + c * 16 + c16;
    const float qt = qterm[b * 1024 + col];
    const float w1c = W1[(size_t)2048 * 1024 + col];
    const float w2 = W2[col];
#pragma unroll
    for (int mf = 0; mf < 4; ++mf)
#pragma unroll
      for (int r = 0; r < 4; ++r) {
        float v = acc[c][mf][r] + qt + covv[mf][r] * w1c;
        p_part[mf][r] += fast_tanh(v) * w2;
      }
  }

  // ---- phase 2b: ncols 4..7, full K ----
#pragma unroll
  for (int c = 0; c < 4; ++c)
#pragma unroll
    for (int mf = 0; mf < 4; ++mf) acc[c][mf] = zz;
#pragma unroll
  for (int ks = 0; ks < 32; ++ks) {
    bf16x8 af[4];
#pragma unroll
    for (int mf = 0; mf < 4; ++mf)
      af[mf] = *(const bf16x8*)(Ab + (mf * 16 + c16) * 2048 + ((ks * 64 + q4 * 16) ^ swzr));
#pragma unroll
    for (int c = 0; c < 4; ++c) {
      bf16x8 bv = *(const bf16x8*)(gB + (size_t)(c + 4) * 16384 + ks * 32);
#pragma unroll
      for (int mf = 0; mf < 4; ++mf) acc[c][mf] = MFMA16(af[mf], bv, acc[c][mf]);
    }
  }
#pragma unroll
  for (int c = 0; c < 4; ++c) {
    const int col = w * 128 + (c + 4) * 16 + c16;
    const float qt = qterm[b * 1024 + col];
    const float w1c = W1[(size_t)2048 * 1024 + col];
    const float w2 = W2[col];
#pragma unroll
    for (int mf = 0; mf < 4; ++mf)
#pragma unroll
      for (int r = 0; r < 4; ++r) {
        float v = acc[c][mf][r] + qt + covv[mf][r] * w1c;
        p_part[mf][r] += fast_tanh(v) * w2;
      }
  }

  // ---- reduce: shfl over the 16 col-lanes, then cross-wave via LDS (overlaid on A) ----
  __syncthreads();  // all A reads done; safe to overlay Sred on Ab
  float* Sred = (float*)Ab;  // [8][64]
#pragma unroll
  for (int mf = 0; mf < 4; ++mf)
#pragma unroll
    for (int r = 0; r < 4; ++r) {
      float p = p_part[mf][r];
      p += __shfl_xor(p, 1);
      p += __shfl_xor(p, 2);
      p += __shfl_xor(p, 4);
      p += __shfl_xor(p, 8);
      if (c16 == 0) Sred[w * 64 + mf * 16 + q4 * 4 + r] = p;
    }
  __syncthreads();
  if (tid < 64) {
    float s = 0.f;
#pragma unroll
    for (int ww = 0; ww < 8; ++ww) s += Sred[ww * 64 + tid];
    scores[row0 + tid] = s;
  }
}

// ---------------- softmax over L per batch; writes attention to d_out ----------------
__global__ void softmax_kernel(const float* __restrict__ scores, float* __restrict__ att) {
  const int b = blockIdx.x;
  const int tid = threadIdx.x;
  const float* s = scores + b * 2048;
  float* a = att + b * 2048;
  __shared__ float red[4];
  float mx = -1e30f;
  for (int l = tid; l < 2048; l += 256) mx = fmaxf(mx, s[l]);
#pragma unroll
  for (int o = 1; o < 64; o <<= 1) mx = fmaxf(mx, __shfl_xor(mx, o));
  if ((tid & 63) == 0) red[tid >> 6] = mx;
  __syncthreads();
  mx = fmaxf(fmaxf(red[0], red[1]), fmaxf(red[2], red[3]));
  __syncthreads();
  float sum = 0.f;
  for (int l = tid; l < 2048; l += 256) {
    float e = __expf(s[l] - mx);
    a[l] = e;
    sum += e;
  }
#pragma unroll
  for (int o = 1; o < 64; o <<= 1) sum += __shfl_xor(sum, o);
  if ((tid & 63) == 0) red[tid >> 6] = sum;
  __syncthreads();
  sum = red[0] + red[1] + red[2] + red[3];
  const float inv = 1.0f / sum;
  for (int l = tid; l < 2048; l += 256) a[l] *= inv;
}

// ---------------- ctx_pre[b][j] = sum_l att[b][l] * keys[b][l][j] ----------------
__global__ void ctxpre_kernel(const float* __restrict__ keys, const float* __restrict__ att,
                              float* __restrict__ ctx_pre) {
  const int b = blockIdx.x;   // 16
  const int sl = blockIdx.y;  // 32 slices of 64 rows
  const int tid = threadIdx.x;
  const float* ab = att + b * 2048 + sl * 64;
  const f32x4* kb = (const f32x4*)(keys + ((size_t)b * 2048 + sl * 64) * 1024) + tid;
  f32x4 acc = {0.f, 0.f, 0.f, 0.f};
#pragma unroll 4
  for (int l = 0; l < 64; ++l) acc += kb[(size_t)l * 256] * ab[l];
  float* cp = ctx_pre + b * 1024 + tid * 4;
  atomicAdd(cp + 0, acc.x);
  atomicAdd(cp + 1, acc.y);
  atomicAdd(cp + 2, acc.z);
  atomicAdd(cp + 3, acc.w);
}

// ---------------- context[b][h] = sum_j ctx_pre[b][j] * Wr[j][h] ----------------
__global__ void context_kernel(const float* __restrict__ ctx_pre, const float* __restrict__ Wr,
                               float* __restrict__ out) {
  const int b = blockIdx.y;
  const int h = blockIdx.x * 256 + threadIdx.x;
  const float* cp = ctx_pre + b * 1024;
  float acc = 0.f;
#pragma unroll 8
  for (int j = 0; j < 1024; ++j) acc += cp[j] * Wr[(size_t)j * 512 + h];
  out[b * 512 + h] = acc;
}

extern "C" void kernel_launch(void* const* d_in, const int* in_sizes, int n_in, void* d_out,
                              int out_size, void* d_ws, size_t ws_size, hipStream_t stream) {
  const float* query = (const float*)d_in[0];     // (16,1,1024)
  const float* keys = (const float*)d_in[1];      // (16,2048,1024)
  const float* coverage = (const float*)d_in[2];  // (16,2048,1)
  const float* W1 = (const float*)d_in[3];        // (2049,1024)
  const float* b1 = (const float*)d_in[4];        // (1024,)
  const float* W2 = (const float*)d_in[5];        // (1024,1)
  const float* Wr = (const float*)d_in[6];        // (1024,512)
  float* out = (float*)d_out;
  char* ws = (char*)d_ws;

  float* scores = (float*)ws;                             // 32768 f32 @ 0
  float* ctx_pre = (float*)(ws + 131072);                 // 16384 f32
  float* qterm = (float*)(ws + 196608);                   // 16384 f32
  unsigned short* W1kt = (unsigned short*)(ws + 262144);  // 1M bf16 (2MB)

  float* context_out = out;     // 16*512
  float* att_out = out + 8192;  // 16*2048

  zero_f32<<<dim3(64), dim3(256), 0, stream>>>(ctx_pre, 16384);
  transpose_w1k<<<dim3(16, 16), dim3(256), 0, stream>>>(W1, W1kt);
  qterm_kernel<<<dim3(4, 16), dim3(256), 0, stream>>>(query, W1, b1, qterm);
  gemm_score_kernel<<<dim3(512), dim3(512), 0, stream>>>(keys, W1kt, qterm, coverage, W1, W2,
                                                         scores);
  softmax_kernel<<<dim3(16), dim3(256), 0, stream>>>(scores, att_out);
  ctxpre_kernel<<<dim3(16, 32), dim3(256), 0, stream>>>(keys, att_out, ctx_pre);
  context_kernel<<<dim3(2, 16), dim3(256), 0, stream>>>(ctx_pre, Wr, context_out);
}

// Round 4
// 283.787 us; speedup vs baseline: 1.1360x; 1.1256x over previous
//
#include <hip/hip_runtime.h>
#include <stdint.h>

typedef short bf16x8 __attribute__((ext_vector_type(8)));
typedef float f32x4 __attribute__((ext_vector_type(4)));
typedef unsigned int u32x4 __attribute__((ext_vector_type(4)));

__device__ __forceinline__ uint32_t asu(float f) { union { float f; uint32_t u; } c; c.f = f; return c.u; }

__device__ __forceinline__ uint32_t bf16rne(float f) {
  uint32_t u = asu(f);
  return (u + 0x7FFFu + ((u >> 16) & 1u)) >> 16;
}
__device__ __forceinline__ uint32_t pack2(float lo, float hi) { return bf16rne(lo) | (bf16rne(hi) << 16); }

__device__ __forceinline__ unsigned short f32_to_bf16(float f) { return (unsigned short)bf16rne(f); }

__device__ __forceinline__ float fast_tanh(float x) {
  float e = __builtin_amdgcn_exp2f(x * 2.8853900817779268f);
  return 1.0f - 2.0f * __builtin_amdgcn_rcpf(e + 1.0f);
}

// ---------------- W1k transpose + bf16 convert; also zeroes ctx_pre ----------------
__global__ void transpose_w1k(const float* __restrict__ W1, unsigned short* __restrict__ W1kt,
                              float* __restrict__ ctx_pre) {
  __shared__ float t[64][65];
  const int kb = blockIdx.x * 64;
  const int jb = blockIdx.y * 64;
  const int c = threadIdx.x & 63;
  const int r = threadIdx.x >> 6;  // 0..3
  const int gid = (blockIdx.y * 16 + blockIdx.x) * 256 + threadIdx.x;
  if (gid < 16384) ctx_pre[gid] = 0.f;
#pragma unroll
  for (int i = 0; i < 16; ++i) {
    const int k = i * 4 + r;
    t[k][c] = W1[(size_t)(1024 + kb + k) * 1024 + (jb + c)];
  }
  __syncthreads();
#pragma unroll
  for (int i = 0; i < 16; ++i) {
    const int j = i * 4 + r;
    W1kt[(size_t)(jb + j) * 1024 + (kb + c)] = f32_to_bf16(t[c][j]);
  }
}

// ---------------- qterm[b][j] = b1[j] + sum_k query[b][k]*W1[k][j] ----------------
__global__ void qterm_kernel(const float* __restrict__ query, const float* __restrict__ W1,
                             const float* __restrict__ b1, float* __restrict__ qterm) {
  const int b = blockIdx.y;
  const int j = blockIdx.x * 256 + threadIdx.x;
  const float* q = query + b * 1024;
  float acc = b1[j];
#pragma unroll 8
  for (int k = 0; k < 1024; ++k) acc += q[k] * W1[(size_t)k * 1024 + j];
  qterm[b * 1024 + j] = acc;
}

// ---------------- fused GEMM + tanh + W2-reduce ----------------
// 1024 threads / 16 waves. BM=64 rows/block, full N=1024 (64 cols/wave), K-tiled
// BK=128 with double-buffered reg-staged A (fp32->bf16). acc held across K-loop.
// LDS chunk layout: [64 rows][128 k] bf16, row stride 256B, byte ^= ((row&7)<<4).
#define MFMA16(a, b, c) __builtin_amdgcn_mfma_f32_16x16x32_bf16(a, b, c, 0, 0, 0)

__global__ __launch_bounds__(1024) void gemm_score_kernel(
    const float* __restrict__ keys, const unsigned short* __restrict__ W1kt,
    const float* __restrict__ qterm, const float* __restrict__ coverage,
    const float* __restrict__ W1, const float* __restrict__ W2, float* __restrict__ scores) {
  __shared__ __align__(16) unsigned char Ab[2][16384];
  const int tid = threadIdx.x;
  const int row0 = blockIdx.x * 64;
  const int b = row0 >> 11;  // 2048 rows per batch
  const int w = tid >> 6;    // 0..15
  const int lane = tid & 63;
  const int c16 = lane & 15;
  const int q4 = lane >> 4;

  // staging: 16 threads per row, 8 fp32 each
  const int srow = tid >> 4;
  const int sk = (tid & 15) * 8;
  const float* gA = keys + (size_t)(row0 + srow) * 1024 + sk;
  const int woff = srow * 256 + ((sk * 2) ^ ((srow & 7) << 4));

  // prologue: stage kt=0, issue kt=1
  f32x4 ca = *(const f32x4*)(gA);
  f32x4 cb = *(const f32x4*)(gA + 4);
  {
    u32x4 p;
    p.x = pack2(ca.x, ca.y);
    p.y = pack2(ca.z, ca.w);
    p.z = pack2(cb.x, cb.y);
    p.w = pack2(cb.z, cb.w);
    *(u32x4*)(&Ab[0][woff]) = p;
  }
  ca = *(const f32x4*)(gA + 128);
  cb = *(const f32x4*)(gA + 132);
  __syncthreads();

  const int swzr = (c16 & 7) << 4;
  const unsigned short* gB = W1kt + (size_t)(w * 64 + c16) * 1024 + q4 * 8;

  f32x4 acc[4][4];  // [ni][mf]
  const f32x4 zz = {0.f, 0.f, 0.f, 0.f};
#pragma unroll
  for (int ni = 0; ni < 4; ++ni)
#pragma unroll
    for (int mf = 0; mf < 4; ++mf) acc[ni][mf] = zz;

  for (int kt = 0; kt < 8; ++kt) {
    const unsigned char* Ac = Ab[kt & 1];
#pragma unroll
    for (int ks = 0; ks < 4; ++ks) {
      bf16x8 af[4];
#pragma unroll
      for (int mf = 0; mf < 4; ++mf)
        af[mf] = *(const bf16x8*)(Ac + (mf * 16 + c16) * 256 + ((ks * 64 + q4 * 16) ^ swzr));
      bf16x8 bv[4];
#pragma unroll
      for (int ni = 0; ni < 4; ++ni)
        bv[ni] = *(const bf16x8*)(gB + (size_t)ni * 16384 + kt * 128 + ks * 32);
#pragma unroll
      for (int ni = 0; ni < 4; ++ni)
#pragma unroll
        for (int mf = 0; mf < 4; ++mf) acc[ni][mf] = MFMA16(af[mf], bv[ni], acc[ni][mf]);
    }
    if (kt < 7) {
      // write-late: loads for kt+1 were issued an iteration ago (latency hidden)
      u32x4 p;
      p.x = pack2(ca.x, ca.y);
      p.y = pack2(ca.z, ca.w);
      p.z = pack2(cb.x, cb.y);
      p.w = pack2(cb.z, cb.w);
      *(u32x4*)(&Ab[(kt + 1) & 1][woff]) = p;
      if (kt < 6) {
        // issue-early: loads for kt+2 fly under the next compute phase
        ca = *(const f32x4*)(gA + (kt + 2) * 128);
        cb = *(const f32x4*)(gA + (kt + 2) * 128 + 4);
      }
    }
    __syncthreads();
  }

  // epilogue: v = acc + qterm + cov*W1c; p_part = sum_j tanh(v)*W2[j]
  float covv[4][4];
#pragma unroll
  for (int mf = 0; mf < 4; ++mf)
#pragma unroll
    for (int r = 0; r < 4; ++r) covv[mf][r] = coverage[row0 + mf * 16 + q4 * 4 + r];

  float p_part[4][4];
#pragma unroll
  for (int mf = 0; mf < 4; ++mf)
#pragma unroll
    for (int r = 0; r < 4; ++r) p_part[mf][r] = 0.f;

#pragma unroll
  for (int ni = 0; ni < 4; ++ni) {
    const int col = w * 64 + ni * 16 + c16;
    const float qt = qterm[b * 1024 + col];
    const float w1c = W1[(size_t)2048 * 1024 + col];
    const float w2 = W2[col];
#pragma unroll
    for (int mf = 0; mf < 4; ++mf)
#pragma unroll
      for (int r = 0; r < 4; ++r) {
        float v = acc[ni][mf][r] + qt + covv[mf][r] * w1c;
        p_part[mf][r] += fast_tanh(v) * w2;
      }
  }

  // reduce: shfl over 16 col-lanes, then cross-wave via LDS (overlaid on Ab)
  float* Sred = (float*)Ab;  // [16][64]
#pragma unroll
  for (int mf = 0; mf < 4; ++mf)
#pragma unroll
    for (int r = 0; r < 4; ++r) {
      float p = p_part[mf][r];
      p += __shfl_xor(p, 1);
      p += __shfl_xor(p, 2);
      p += __shfl_xor(p, 4);
      p += __shfl_xor(p, 8);
      if (c16 == 0) Sred[w * 64 + mf * 16 + q4 * 4 + r] = p;
    }
  __syncthreads();
  if (tid < 64) {
    float s = 0.f;
#pragma unroll
    for (int ww = 0; ww < 16; ++ww) s += Sred[ww * 64 + tid];
    scores[row0 + tid] = s;
  }
}

// ---------------- softmax over L per batch; writes attention to d_out ----------------
__global__ void softmax_kernel(const float* __restrict__ scores, float* __restrict__ att) {
  const int b = blockIdx.x;
  const int tid = threadIdx.x;
  const float* s = scores + b * 2048;
  float* a = att + b * 2048;
  __shared__ float red[4];
  float mx = -1e30f;
  for (int l = tid; l < 2048; l += 256) mx = fmaxf(mx, s[l]);
#pragma unroll
  for (int o = 1; o < 64; o <<= 1) mx = fmaxf(mx, __shfl_xor(mx, o));
  if ((tid & 63) == 0) red[tid >> 6] = mx;
  __syncthreads();
  mx = fmaxf(fmaxf(red[0], red[1]), fmaxf(red[2], red[3]));
  __syncthreads();
  float sum = 0.f;
  for (int l = tid; l < 2048; l += 256) {
    float e = __expf(s[l] - mx);
    a[l] = e;
    sum += e;
  }
#pragma unroll
  for (int o = 1; o < 64; o <<= 1) sum += __shfl_xor(sum, o);
  if ((tid & 63) == 0) red[tid >> 6] = sum;
  __syncthreads();
  sum = red[0] + red[1] + red[2] + red[3];
  const float inv = 1.0f / sum;
  for (int l = tid; l < 2048; l += 256) a[l] *= inv;
}

// ---------------- ctx_pre[b][j] = sum_l att[b][l] * keys[b][l][j] ----------------
__global__ void ctxpre_kernel(const float* __restrict__ keys, const float* __restrict__ att,
                              float* __restrict__ ctx_pre) {
  const int b = blockIdx.x;   // 16
  const int sl = blockIdx.y;  // 32 slices of 64 rows
  const int tid = threadIdx.x;
  const float* ab = att + b * 2048 + sl * 64;
  const f32x4* kb = (const f32x4*)(keys + ((size_t)b * 2048 + sl * 64) * 1024) + tid;
  f32x4 acc = {0.f, 0.f, 0.f, 0.f};
#pragma unroll 4
  for (int l = 0; l < 64; ++l) acc += kb[(size_t)l * 256] * ab[l];
  float* cp = ctx_pre + b * 1024 + tid * 4;
  atomicAdd(cp + 0, acc.x);
  atomicAdd(cp + 1, acc.y);
  atomicAdd(cp + 2, acc.z);
  atomicAdd(cp + 3, acc.w);
}

// ---------------- context[b][h] = sum_j ctx_pre[b][j] * Wr[j][h] ----------------
__global__ void context_kernel(const float* __restrict__ ctx_pre, const float* __restrict__ Wr,
                               float* __restrict__ out) {
  const int b = blockIdx.y;
  const int h = blockIdx.x * 256 + threadIdx.x;
  const float* cp = ctx_pre + b * 1024;
  float acc = 0.f;
#pragma unroll 8
  for (int j = 0; j < 1024; ++j) acc += cp[j] * Wr[(size_t)j * 512 + h];
  out[b * 512 + h] = acc;
}

extern "C" void kernel_launch(void* const* d_in, const int* in_sizes, int n_in, void* d_out,
                              int out_size, void* d_ws, size_t ws_size, hipStream_t stream) {
  const float* query = (const float*)d_in[0];     // (16,1,1024)
  const float* keys = (const float*)d_in[1];      // (16,2048,1024)
  const float* coverage = (const float*)d_in[2];  // (16,2048,1)
  const float* W1 = (const float*)d_in[3];        // (2049,1024)
  const float* b1 = (const float*)d_in[4];        // (1024,)
  const float* W2 = (const float*)d_in[5];        // (1024,1)
  const float* Wr = (const float*)d_in[6];        // (1024,512)
  float* out = (float*)d_out;
  char* ws = (char*)d_ws;

  float* scores = (float*)ws;                             // 32768 f32 @ 0
  float* ctx_pre = (float*)(ws + 131072);                 // 16384 f32
  float* qterm = (float*)(ws + 196608);                   // 16384 f32
  unsigned short* W1kt = (unsigned short*)(ws + 262144);  // 1M bf16 (2MB)

  float* context_out = out;     // 16*512
  float* att_out = out + 8192;  // 16*2048

  transpose_w1k<<<dim3(16, 16), dim3(256), 0, stream>>>(W1, W1kt, ctx_pre);
  qterm_kernel<<<dim3(4, 16), dim3(256), 0, stream>>>(query, W1, b1, qterm);
  gemm_score_kernel<<<dim3(512), dim3(1024), 0, stream>>>(keys, W1kt, qterm, coverage, W1, W2,
                                                          scores);
  softmax_kernel<<<dim3(16), dim3(256), 0, stream>>>(scores, att_out);
  ctxpre_kernel<<<dim3(16, 32), dim3(256), 0, stream>>>(keys, att_out, ctx_pre);
  context_kernel<<<dim3(2, 16), dim3(256), 0, stream>>>(ctx_pre, Wr, context_out);
}